// Round 6
// baseline (339.938 us; speedup 1.0000x reference)
//
#include <hip/hip_runtime.h>
#include <hip/hip_bf16.h>

#define K1 195
#define K1P 224
#define K2 131
#define K2P 160
#define OC 256
#define BM 64
#define S1 232   // LDS row stride (bf16 elems): 464 B; row-to-row bank shift 20 -> max 2-way (free)

typedef __attribute__((ext_vector_type(4))) float f32x4;
typedef __attribute__((ext_vector_type(8))) short bf16x8;

__global__ void prep_weights_v6(const float* __restrict__ Wc, const float* __restrict__ Wa,
                                __hip_bfloat16* __restrict__ WcP, __hip_bfloat16* __restrict__ WaP) {
    int t = blockIdx.x * blockDim.x + threadIdx.x;
    const int total1 = OC * K1P;
    const int total2 = OC * K2P;
    if (t < total1) {
        int oc = t / K1P, k = t - oc * K1P;
        float v = (k < K1) ? Wc[oc * K1 + k] : 0.0f;
        WcP[t] = __float2bfloat16(v);
    } else if (t < total1 + total2) {
        int u = t - total1;
        int oc = u / K2P, k = u - oc * K2P;
        float v = (k < K2) ? Wa[oc * K2 + k] : 0.0f;
        WaP[u] = __float2bfloat16(v);
    }
}

__global__ __launch_bounds__(256) void fused_mesh_v6(
        const float* __restrict__ spatial,
        const float* __restrict__ structural,
        const int* __restrict__ neighbour,
        const __hip_bfloat16* __restrict__ WcP,
        const float* __restrict__ bc,
        const __hip_bfloat16* __restrict__ WaP,
        const float* __restrict__ ba,
        float* __restrict__ out1,
        float* __restrict__ out2,
        int n) {
    // ONE reused LDS buffer (30.5 KB/block):
    //   phase 1: A1 = concat(bf16(spatial), bf16(structural_self)) -> GEMM1
    //   phase 2: A1[:,0:160) = gathered mean (zero-padded)         -> GEMM2
    __shared__ __hip_bfloat16 A1[BM][S1];
    __shared__ int nidx[BM * 3];

    const int t = threadIdx.x;
    const int r0 = blockIdx.x * BM;

    // ---- stage neighbour indices (round-2 verbatim) ----
    if (t < BM * 3) {
        size_t gi = (size_t)r0 * 3 + t;
        nidx[t] = (gi < (size_t)n * 3) ? neighbour[gi] : 0;
    }

    // ---- zero-pad cols [195,224) (round-2 verbatim) ----
    for (int e = t; e < BM * (K1P - K1); e += 256) {
        int r = e / (K1P - K1);
        int k = K1 + (e - r * (K1P - K1));
        A1[r][k] = __float2bfloat16(0.0f);
    }

    // ---- spatial -> A1[:,0:64] (round-2 verbatim, incl. clamp) ----
    {
        int r = t >> 2;
        int c0 = (t & 3) * 16;
        int rr = min(r0 + r, n - 1);
        const f32x4* src = (const f32x4*)(spatial + (size_t)rr * 64 + c0);
        #pragma unroll
        for (int i = 0; i < 4; ++i) {
            f32x4 v = src[i];
            #pragma unroll
            for (int j = 0; j < 4; ++j)
                A1[r][c0 + i * 4 + j] = __float2bfloat16(v[j]);
        }
    }
    __syncthreads();  // nidx ready

    // ---- structural self -> A1[:,64:195] (round-2 loop minus neighbor part) ----
    for (int e = t; e < BM * K2; e += 256) {
        int r = e / K2;
        int k = e - r * K2;
        int rr = min(r0 + r, n - 1);
        float self = structural[(size_t)rr * K2 + k];
        A1[r][64 + k] = __float2bfloat16(self);
    }
    __syncthreads();

    // ---- MFMA GEMMs: wave w owns cols [w*64, w*64+64) for all 64 rows ----
    const int wid  = t >> 6;
    const int lane = t & 63;
    const int lr   = lane & 15;   // fragment row (A) / col (B,D)
    const int lkc  = lane >> 4;   // k-chunk 0..3 (each 8 elems)
    const int colBase = wid * 64;

    // ---- GEMM 1: out1 = A1 * WcP^T + bc (round-2 verbatim) ----
    {
        f32x4 acc[4][4];
        #pragma unroll
        for (int i = 0; i < 4; ++i)
            #pragma unroll
            for (int j = 0; j < 4; ++j)
                acc[i][j] = (f32x4){0.f, 0.f, 0.f, 0.f};

        #pragma unroll
        for (int ks = 0; ks < K1P; ks += 32) {
            bf16x8 a[4], b[4];
            #pragma unroll
            for (int rt = 0; rt < 4; ++rt)
                a[rt] = *(const bf16x8*)&A1[rt * 16 + lr][ks + lkc * 8];
            #pragma unroll
            for (int ct = 0; ct < 4; ++ct) {
                int oc = colBase + ct * 16 + lr;
                b[ct] = *(const bf16x8*)(WcP + (size_t)oc * K1P + ks + lkc * 8);
            }
            #pragma unroll
            for (int rt = 0; rt < 4; ++rt)
                #pragma unroll
                for (int ct = 0; ct < 4; ++ct)
                    acc[rt][ct] = __builtin_amdgcn_mfma_f32_16x16x32_bf16(a[rt], b[ct], acc[rt][ct], 0, 0, 0);
        }

        #pragma unroll
        for (int ct = 0; ct < 4; ++ct) {
            int col = colBase + ct * 16 + lr;
            float bias = bc[col];
            #pragma unroll
            for (int rt = 0; rt < 4; ++rt) {
                #pragma unroll
                for (int j = 0; j < 4; ++j) {
                    int row = r0 + rt * 16 + lkc * 4 + j;
                    if (row < n)
                        out1[(size_t)row * OC + col] = acc[rt][ct][j] + bias;
                }
            }
        }
    }

    __syncthreads();  // all GEMM1 LDS reads complete before overwrite

    // ---- gather+average -> A1[:,0:131), zeros [131,160) (round-2 math, clamp kept) ----
    for (int e = t; e < BM * K2; e += 256) {
        int r = e / K2;
        int k = e - r * K2;
        int rr = min(r0 + r, n - 1);
        float self = structural[(size_t)rr * K2 + k];  // cache hit (phase-1 lines)
        int n0 = nidx[r * 3 + 0];
        int n1 = nidx[r * 3 + 1];
        int n2 = nidx[r * 3 + 2];
        float v = self + structural[(size_t)n0 * K2 + k]
                       + structural[(size_t)n1 * K2 + k]
                       + structural[(size_t)n2 * K2 + k];
        A1[r][k] = __float2bfloat16(v * 0.25f);
    }
    for (int e = t; e < BM * (K2P - K2); e += 256) {
        int r = e / (K2P - K2);
        int k = K2 + (e - r * (K2P - K2));
        A1[r][k] = __float2bfloat16(0.0f);
    }
    __syncthreads();

    // ---- GEMM 2: out2 = A1 * WaP^T + ba (round-2 verbatim, buffer renamed) ----
    {
        f32x4 acc[4][4];
        #pragma unroll
        for (int i = 0; i < 4; ++i)
            #pragma unroll
            for (int j = 0; j < 4; ++j)
                acc[i][j] = (f32x4){0.f, 0.f, 0.f, 0.f};

        #pragma unroll
        for (int ks = 0; ks < K2P; ks += 32) {
            bf16x8 a[4], b[4];
            #pragma unroll
            for (int rt = 0; rt < 4; ++rt)
                a[rt] = *(const bf16x8*)&A1[rt * 16 + lr][ks + lkc * 8];
            #pragma unroll
            for (int ct = 0; ct < 4; ++ct) {
                int oc = colBase + ct * 16 + lr;
                b[ct] = *(const bf16x8*)(WaP + (size_t)oc * K2P + ks + lkc * 8);
            }
            #pragma unroll
            for (int rt = 0; rt < 4; ++rt)
                #pragma unroll
                for (int ct = 0; ct < 4; ++ct)
                    acc[rt][ct] = __builtin_amdgcn_mfma_f32_16x16x32_bf16(a[rt], b[ct], acc[rt][ct], 0, 0, 0);
        }

        #pragma unroll
        for (int ct = 0; ct < 4; ++ct) {
            int col = colBase + ct * 16 + lr;
            float bias = ba[col];
            #pragma unroll
            for (int rt = 0; rt < 4; ++rt) {
                #pragma unroll
                for (int j = 0; j < 4; ++j) {
                    int row = r0 + rt * 16 + lkc * 4 + j;
                    if (row < n)
                        out2[(size_t)row * OC + col] = acc[rt][ct][j] + bias;
                }
            }
        }
    }
}

extern "C" void kernel_launch(void* const* d_in, const int* in_sizes, int n_in,
                              void* d_out, int out_size, void* d_ws, size_t ws_size,
                              hipStream_t stream) {
    const float* spatial    = (const float*)d_in[0];
    const float* structural = (const float*)d_in[1];
    const int*   neighbour  = (const int*)d_in[2];
    const float* Wc = (const float*)d_in[3];
    const float* bc = (const float*)d_in[4];
    const float* Wa = (const float*)d_in[5];
    const float* ba = (const float*)d_in[6];

    const int n = in_sizes[0] / 64;  // 200000

    float* out1 = (float*)d_out;
    float* out2 = out1 + (size_t)n * OC;

    __hip_bfloat16* WcP = (__hip_bfloat16*)d_ws;
    __hip_bfloat16* WaP = WcP + OC * K1P;

    {
        const int total = OC * K1P + OC * K2P;
        prep_weights_v6<<<(total + 255) / 256, 256, 0, stream>>>(Wc, Wa, WcP, WaP);
    }
    {
        const int grid = (n + BM - 1) / BM;  // 3125
        fused_mesh_v6<<<grid, 256, 0, stream>>>(spatial, structural, neighbour,
                                                WcP, bc, WaP, ba, out1, out2, n);
    }
}

// Round 7
// 205.271 us; speedup vs baseline: 1.6561x; 1.6561x over previous
//
#include <hip/hip_runtime.h>
#include <hip/hip_bf16.h>

#define K1 195
#define K1P 224
#define K2 131
#define K2P 160
#define OC 256
#define BM 64
#define S1 232   // LDS row stride for A1 (bf16 elems): 464 B
#define S2 168   // LDS row stride for A2: 336 B

typedef __attribute__((ext_vector_type(4))) float f32x4;
typedef __attribute__((ext_vector_type(8))) short bf16x8;

__global__ void prep_weights_v7(const float* __restrict__ Wc, const float* __restrict__ Wa,
                                __hip_bfloat16* __restrict__ WcP, __hip_bfloat16* __restrict__ WaP) {
    int t = blockIdx.x * blockDim.x + threadIdx.x;
    const int total1 = OC * K1P;
    const int total2 = OC * K2P;
    if (t < total1) {
        int oc = t / K1P, k = t - oc * K1P;
        float v = (k < K1) ? Wc[oc * K1 + k] : 0.0f;
        WcP[t] = __float2bfloat16(v);
    } else if (t < total1 + total2) {
        int u = t - total1;
        int oc = u / K2P, k = u - oc * K2P;
        float v = (k < K2) ? Wa[oc * K2 + k] : 0.0f;
        WaP[u] = __float2bfloat16(v);
    }
}

__global__ __launch_bounds__(256) void fused_mesh_v7(
        const float* __restrict__ spatial,
        const float* __restrict__ structural,
        const int* __restrict__ neighbour,
        const __hip_bfloat16* __restrict__ WcP,
        const float* __restrict__ bc,
        const __hip_bfloat16* __restrict__ WaP,
        const float* __restrict__ ba,
        float* __restrict__ out1,
        float* __restrict__ out2,
        int n) {
    __shared__ __hip_bfloat16 A1[BM][S1];
    __shared__ __hip_bfloat16 A2[BM][S2];
    __shared__ int nidx[BM * 3];

    const int t = threadIdx.x;
    const int r0 = blockIdx.x * BM;

    // ---- stage neighbour indices (R2 verbatim) ----
    if (t < BM * 3) {
        size_t gi = (size_t)r0 * 3 + t;
        nidx[t] = (gi < (size_t)n * 3) ? neighbour[gi] : 0;
    }

    // ---- zero-pad K tails (R2 verbatim) ----
    for (int e = t; e < BM * (K1P - K1); e += 256) {
        int r = e / (K1P - K1);
        int k = K1 + (e - r * (K1P - K1));
        A1[r][k] = __float2bfloat16(0.0f);
    }
    for (int e = t; e < BM * (K2P - K2); e += 256) {
        int r = e / (K2P - K2);
        int k = K2 + (e - r * (K2P - K2));
        A2[r][k] = __float2bfloat16(0.0f);
    }

    // ---- spatial -> A1[:, 0:64] (R2 verbatim) ----
    {
        int r = t >> 2;
        int c0 = (t & 3) * 16;
        int rr = min(r0 + r, n - 1);
        const f32x4* src = (const f32x4*)(spatial + (size_t)rr * 64 + c0);
        #pragma unroll
        for (int i = 0; i < 4; ++i) {
            f32x4 v = src[i];
            #pragma unroll
            for (int j = 0; j < 4; ++j)
                A1[r][c0 + i * 4 + j] = __float2bfloat16(v[j]);
        }
    }
    __syncthreads();  // nidx ready

    // ---- structural self + gather -> A1[:,64:195], A2[:,0:131] (R2 verbatim) ----
    for (int e = t; e < BM * K2; e += 256) {
        int r = e / K2;
        int k = e - r * K2;
        int rr = min(r0 + r, n - 1);
        float self = structural[(size_t)rr * K2 + k];
        int n0 = nidx[r * 3 + 0];
        int n1 = nidx[r * 3 + 1];
        int n2 = nidx[r * 3 + 2];
        float v = self + structural[(size_t)n0 * K2 + k]
                       + structural[(size_t)n1 * K2 + k]
                       + structural[(size_t)n2 * K2 + k];
        A1[r][64 + k] = __float2bfloat16(self);
        A2[r][k]      = __float2bfloat16(v * 0.25f);
    }
    __syncthreads();

    // ---- MFMA GEMMs: wave w owns oc cols [w*64, w*64+64) for all 64 nodes ----
    // SWAPPED operands: A-operand = weights (M=oc), B-operand = nodes (N=node).
    // D layout: col(lane&15) = node, row((lane>>4)*4+j) = oc -> j gives 4
    // CONSECUTIVE oc per lane -> one dwordx4 store per fragment.
    const int wid  = t >> 6;
    const int lane = t & 63;
    const int lr   = lane & 15;
    const int lkc  = lane >> 4;
    const int colBase = wid * 64;

    // ---- GEMM 1: out1 = A1 * WcP^T + bc ----
    {
        f32x4 acc[4][4];  // [ct = oc tile][rt = node tile]
        #pragma unroll
        for (int i = 0; i < 4; ++i)
            #pragma unroll
            for (int j = 0; j < 4; ++j)
                acc[i][j] = (f32x4){0.f, 0.f, 0.f, 0.f};

        #pragma unroll
        for (int ks = 0; ks < K1P; ks += 32) {
            bf16x8 a[4], b[4];
            #pragma unroll
            for (int rt = 0; rt < 4; ++rt)
                a[rt] = *(const bf16x8*)&A1[rt * 16 + lr][ks + lkc * 8];
            #pragma unroll
            for (int ct = 0; ct < 4; ++ct) {
                int oc = colBase + ct * 16 + lr;
                b[ct] = *(const bf16x8*)(WcP + (size_t)oc * K1P + ks + lkc * 8);
            }
            #pragma unroll
            for (int rt = 0; rt < 4; ++rt)
                #pragma unroll
                for (int ct = 0; ct < 4; ++ct)
                    acc[ct][rt] = __builtin_amdgcn_mfma_f32_16x16x32_bf16(b[ct], a[rt], acc[ct][rt], 0, 0, 0);
        }

        #pragma unroll
        for (int ct = 0; ct < 4; ++ct) {
            int oc0 = colBase + ct * 16 + lkc * 4;
            f32x4 b4 = *(const f32x4*)(bc + oc0);
            #pragma unroll
            for (int rt = 0; rt < 4; ++rt) {
                int node = r0 + rt * 16 + lr;
                if (node < n) {
                    f32x4 v = acc[ct][rt] + b4;
                    __builtin_nontemporal_store(v, (f32x4*)(out1 + (size_t)node * OC + oc0));
                }
            }
        }
    }

    // ---- GEMM 2: out2 = A2 * WaP^T + ba ----
    {
        f32x4 acc[4][4];
        #pragma unroll
        for (int i = 0; i < 4; ++i)
            #pragma unroll
            for (int j = 0; j < 4; ++j)
                acc[i][j] = (f32x4){0.f, 0.f, 0.f, 0.f};

        #pragma unroll
        for (int ks = 0; ks < K2P; ks += 32) {
            bf16x8 a[4], b[4];
            #pragma unroll
            for (int rt = 0; rt < 4; ++rt)
                a[rt] = *(const bf16x8*)&A2[rt * 16 + lr][ks + lkc * 8];
            #pragma unroll
            for (int ct = 0; ct < 4; ++ct) {
                int oc = colBase + ct * 16 + lr;
                b[ct] = *(const bf16x8*)(WaP + (size_t)oc * K2P + ks + lkc * 8);
            }
            #pragma unroll
            for (int rt = 0; rt < 4; ++rt)
                #pragma unroll
                for (int ct = 0; ct < 4; ++ct)
                    acc[ct][rt] = __builtin_amdgcn_mfma_f32_16x16x32_bf16(b[ct], a[rt], acc[ct][rt], 0, 0, 0);
        }

        #pragma unroll
        for (int ct = 0; ct < 4; ++ct) {
            int oc0 = colBase + ct * 16 + lkc * 4;
            f32x4 b4 = *(const f32x4*)(ba + oc0);
            #pragma unroll
            for (int rt = 0; rt < 4; ++rt) {
                int node = r0 + rt * 16 + lr;
                if (node < n) {
                    f32x4 v = acc[ct][rt] + b4;
                    __builtin_nontemporal_store(v, (f32x4*)(out2 + (size_t)node * OC + oc0));
                }
            }
        }
    }
}

extern "C" void kernel_launch(void* const* d_in, const int* in_sizes, int n_in,
                              void* d_out, int out_size, void* d_ws, size_t ws_size,
                              hipStream_t stream) {
    const float* spatial    = (const float*)d_in[0];
    const float* structural = (const float*)d_in[1];
    const int*   neighbour  = (const int*)d_in[2];
    const float* Wc = (const float*)d_in[3];
    const float* bc = (const float*)d_in[4];
    const float* Wa = (const float*)d_in[5];
    const float* ba = (const float*)d_in[6];

    const int n = in_sizes[0] / 64;  // 200000

    float* out1 = (float*)d_out;
    float* out2 = out1 + (size_t)n * OC;

    __hip_bfloat16* WcP = (__hip_bfloat16*)d_ws;
    __hip_bfloat16* WaP = WcP + OC * K1P;

    {
        const int total = OC * K1P + OC * K2P;
        prep_weights_v7<<<(total + 255) / 256, 256, 0, stream>>>(Wc, Wa, WcP, WaP);
    }
    {
        const int grid = (n + BM - 1) / BM;  // 3125
        fused_mesh_v7<<<grid, 256, 0, stream>>>(spatial, structural, neighbour,
                                                WcP, bc, WaP, ba, out1, out2, n);
    }
}

// Round 8
// 191.568 us; speedup vs baseline: 1.7745x; 1.0715x over previous
//
#include <hip/hip_runtime.h>
#include <hip/hip_bf16.h>

#define K1 195
#define K1P 224
#define K2 131
#define K2P 160
#define OC 256
#define BM 32
#define S1 232   // LDS row stride for A1 (bf16 elems): 464 B
#define S2 168   // LDS row stride for A2: 336 B

typedef __attribute__((ext_vector_type(4))) float f32x4;
typedef __attribute__((ext_vector_type(8))) short bf16x8;

__global__ void prep_weights_v8(const float* __restrict__ Wc, const float* __restrict__ Wa,
                                __hip_bfloat16* __restrict__ WcP, __hip_bfloat16* __restrict__ WaP) {
    int t = blockIdx.x * blockDim.x + threadIdx.x;
    const int total1 = OC * K1P;
    const int total2 = OC * K2P;
    if (t < total1) {
        int oc = t / K1P, k = t - oc * K1P;
        float v = (k < K1) ? Wc[oc * K1 + k] : 0.0f;
        WcP[t] = __float2bfloat16(v);
    } else if (t < total1 + total2) {
        int u = t - total1;
        int oc = u / K2P, k = u - oc * K2P;
        float v = (k < K2) ? Wa[oc * K2 + k] : 0.0f;
        WaP[u] = __float2bfloat16(v);
    }
}

__global__ __launch_bounds__(256) void fused_mesh_v8(
        const float* __restrict__ spatial,
        const float* __restrict__ structural,
        const int* __restrict__ neighbour,
        const __hip_bfloat16* __restrict__ WcP,
        const float* __restrict__ bc,
        const __hip_bfloat16* __restrict__ WaP,
        const float* __restrict__ ba,
        float* __restrict__ out1,
        float* __restrict__ out2,
        int n) {
    __shared__ __hip_bfloat16 A1[BM][S1];
    __shared__ __hip_bfloat16 A2[BM][S2];
    __shared__ int nidx[BM * 3];

    const int t = threadIdx.x;
    const int r0 = blockIdx.x * BM;

    // ---- stage neighbour indices ----
    if (t < BM * 3) {
        size_t gi = (size_t)r0 * 3 + t;
        nidx[t] = (gi < (size_t)n * 3) ? neighbour[gi] : 0;
    }

    // ---- zero-pad K tails ----
    for (int e = t; e < BM * (K1P - K1); e += 256) {
        int r = e / (K1P - K1);
        int k = K1 + (e - r * (K1P - K1));
        A1[r][k] = __float2bfloat16(0.0f);
    }
    for (int e = t; e < BM * (K2P - K2); e += 256) {
        int r = e / (K2P - K2);
        int k = K2 + (e - r * (K2P - K2));
        A2[r][k] = __float2bfloat16(0.0f);
    }

    // ---- spatial -> A1[:, 0:64] : 32 rows x 64 cols, 8 floats/thread ----
    {
        int r = t >> 3;               // 0..31
        int c0 = (t & 7) * 8;         // 0,8,..,56
        int rr = min(r0 + r, n - 1);
        const float* src = spatial + (size_t)rr * 64 + c0;
        f32x4 v0 = *(const f32x4*)src;
        f32x4 v1 = *(const f32x4*)(src + 4);
        bf16x8 o;
        #pragma unroll
        for (int j = 0; j < 4; ++j) {
            __hip_bfloat16 h0 = __float2bfloat16(v0[j]);
            __hip_bfloat16 h1 = __float2bfloat16(v1[j]);
            o[j]     = *reinterpret_cast<short*>(&h0);
            o[4 + j] = *reinterpret_cast<short*>(&h1);
        }
        *(bf16x8*)&A1[r][c0] = o;
    }
    __syncthreads();  // nidx ready

    // ---- structural self + gather -> A1[:,64:195], A2[:,0:131] ----
    for (int e = t; e < BM * K2; e += 256) {
        int r = e / K2;
        int k = e - r * K2;
        int rr = min(r0 + r, n - 1);
        float self = structural[(size_t)rr * K2 + k];
        int n0 = nidx[r * 3 + 0];
        int n1 = nidx[r * 3 + 1];
        int n2 = nidx[r * 3 + 2];
        float v = self + structural[(size_t)n0 * K2 + k]
                       + structural[(size_t)n1 * K2 + k]
                       + structural[(size_t)n2 * K2 + k];
        A1[r][64 + k] = __float2bfloat16(self);
        A2[r][k]      = __float2bfloat16(v * 0.25f);
    }
    __syncthreads();

    // ---- MFMA GEMMs, swapped operands (A=weights, B=nodes) ----
    // D layout: col(lane&15) = node, row((lane>>4)*4+j) = oc -> 4 consecutive
    // oc per lane -> dwordx4 nontemporal stores.
    const int wid  = t >> 6;
    const int lane = t & 63;
    const int lr   = lane & 15;
    const int lkc  = lane >> 4;
    const int colBase = wid * 64;

    // ---- GEMM 1: out1 = A1 * WcP^T + bc ----
    {
        f32x4 acc[4][2];  // [ct = oc tile][rt = node tile]
        #pragma unroll
        for (int i = 0; i < 4; ++i)
            #pragma unroll
            for (int j = 0; j < 2; ++j)
                acc[i][j] = (f32x4){0.f, 0.f, 0.f, 0.f};

        #pragma unroll
        for (int ks = 0; ks < K1P; ks += 32) {
            bf16x8 a[2], b[4];
            #pragma unroll
            for (int rt = 0; rt < 2; ++rt)
                a[rt] = *(const bf16x8*)&A1[rt * 16 + lr][ks + lkc * 8];
            #pragma unroll
            for (int ct = 0; ct < 4; ++ct) {
                int oc = colBase + ct * 16 + lr;
                b[ct] = *(const bf16x8*)(WcP + (size_t)oc * K1P + ks + lkc * 8);
            }
            #pragma unroll
            for (int rt = 0; rt < 2; ++rt)
                #pragma unroll
                for (int ct = 0; ct < 4; ++ct)
                    acc[ct][rt] = __builtin_amdgcn_mfma_f32_16x16x32_bf16(b[ct], a[rt], acc[ct][rt], 0, 0, 0);
        }

        #pragma unroll
        for (int ct = 0; ct < 4; ++ct) {
            int oc0 = colBase + ct * 16 + lkc * 4;
            f32x4 b4 = *(const f32x4*)(bc + oc0);
            #pragma unroll
            for (int rt = 0; rt < 2; ++rt) {
                int node = r0 + rt * 16 + lr;
                if (node < n) {
                    f32x4 v = acc[ct][rt] + b4;
                    __builtin_nontemporal_store(v, (f32x4*)(out1 + (size_t)node * OC + oc0));
                }
            }
        }
    }

    // ---- GEMM 2: out2 = A2 * WaP^T + ba ----
    {
        f32x4 acc[4][2];
        #pragma unroll
        for (int i = 0; i < 4; ++i)
            #pragma unroll
            for (int j = 0; j < 2; ++j)
                acc[i][j] = (f32x4){0.f, 0.f, 0.f, 0.f};

        #pragma unroll
        for (int ks = 0; ks < K2P; ks += 32) {
            bf16x8 a[2], b[4];
            #pragma unroll
            for (int rt = 0; rt < 2; ++rt)
                a[rt] = *(const bf16x8*)&A2[rt * 16 + lr][ks + lkc * 8];
            #pragma unroll
            for (int ct = 0; ct < 4; ++ct) {
                int oc = colBase + ct * 16 + lr;
                b[ct] = *(const bf16x8*)(WaP + (size_t)oc * K2P + ks + lkc * 8);
            }
            #pragma unroll
            for (int rt = 0; rt < 2; ++rt)
                #pragma unroll
                for (int ct = 0; ct < 4; ++ct)
                    acc[ct][rt] = __builtin_amdgcn_mfma_f32_16x16x32_bf16(b[ct], a[rt], acc[ct][rt], 0, 0, 0);
        }

        #pragma unroll
        for (int ct = 0; ct < 4; ++ct) {
            int oc0 = colBase + ct * 16 + lkc * 4;
            f32x4 b4 = *(const f32x4*)(ba + oc0);
            #pragma unroll
            for (int rt = 0; rt < 2; ++rt) {
                int node = r0 + rt * 16 + lr;
                if (node < n) {
                    f32x4 v = acc[ct][rt] + b4;
                    __builtin_nontemporal_store(v, (f32x4*)(out2 + (size_t)node * OC + oc0));
                }
            }
        }
    }
}

extern "C" void kernel_launch(void* const* d_in, const int* in_sizes, int n_in,
                              void* d_out, int out_size, void* d_ws, size_t ws_size,
                              hipStream_t stream) {
    const float* spatial    = (const float*)d_in[0];
    const float* structural = (const float*)d_in[1];
    const int*   neighbour  = (const int*)d_in[2];
    const float* Wc = (const float*)d_in[3];
    const float* bc = (const float*)d_in[4];
    const float* Wa = (const float*)d_in[5];
    const float* ba = (const float*)d_in[6];

    const int n = in_sizes[0] / 64;  // 200000

    float* out1 = (float*)d_out;
    float* out2 = out1 + (size_t)n * OC;

    __hip_bfloat16* WcP = (__hip_bfloat16*)d_ws;
    __hip_bfloat16* WaP = WcP + OC * K1P;

    {
        const int total = OC * K1P + OC * K2P;
        prep_weights_v8<<<(total + 255) / 256, 256, 0, stream>>>(Wc, Wa, WcP, WaP);
    }
    {
        const int grid = (n + BM - 1) / BM;  // 6250
        fused_mesh_v8<<<grid, 256, 0, stream>>>(spatial, structural, neighbour,
                                                WcP, bc, WaP, ba, out1, out2, n);
    }
}